// Round 12
// baseline (104.583 us; speedup 1.0000x reference)
//
#include <hip/hip_runtime.h>

typedef unsigned short u16;
typedef unsigned int u32;
typedef __attribute__((ext_vector_type(8))) short bf16x8;
typedef __attribute__((ext_vector_type(4))) float f32x4;
typedef __attribute__((ext_vector_type(16))) float f32x16;

#define LOG2E 1.4426950408889634f
#define QSCALE (0.125f * LOG2E)

__device__ __forceinline__ u16 f2bf(float f) {
  union { float f; u32 u; } x; x.f = f;
  u32 r = x.u + 0x7fffu + ((x.u >> 16) & 1u);   // RNE; inputs are finite
  return (u16)(r >> 16);
}

__device__ __forceinline__ u32 cvtpk(float a, float b) {
  u32 r;
  asm("v_cvt_pk_bf16_f32 %0, %1, %2" : "=v"(r) : "v"(a), "v"(b));
  return r;
}

__device__ __forceinline__ bf16x8 mkfrag(u32 a, u32 b, u32 c, u32 d) {
  union { u32 w[4]; bf16x8 v; } u;
  u.w[0] = a; u.w[1] = b; u.w[2] = c; u.w[3] = d;
  return u.v;
}

__device__ __forceinline__ void gload_lds16(const void* g, void* l) {
  __builtin_amdgcn_global_load_lds((const __attribute__((address_space(1))) u32*)g,
                                   (__attribute__((address_space(3))) u32*)l, 16, 0, 0);
}

// pack 32 P-values (f32) -> two A-fragments via cvt_pk + lo/hi half exchange (T12)
__device__ __forceinline__ void packP(const f32x16& s, int hi, bf16x8& P0, bf16x8& P1) {
  u32 w0 = cvtpk(s[0], s[1]),  w1 = cvtpk(s[2], s[3]);
  u32 w2 = cvtpk(s[4], s[5]),  w3 = cvtpk(s[6], s[7]);
  u32 w4 = cvtpk(s[8], s[9]),  w5 = cvtpk(s[10], s[11]);
  u32 w6 = cvtpk(s[12], s[13]), w7 = cvtpk(s[14], s[15]);
  u32 x0 = __shfl_xor((int)w0, 32), x1 = __shfl_xor((int)w1, 32);
  u32 x2 = __shfl_xor((int)w2, 32), x3 = __shfl_xor((int)w3, 32);
  u32 x4 = __shfl_xor((int)w4, 32), x5 = __shfl_xor((int)w5, 32);
  u32 x6 = __shfl_xor((int)w6, 32), x7 = __shfl_xor((int)w7, 32);
  P0 = mkfrag(hi ? x2 : w0, hi ? x3 : w1, hi ? w2 : x0, hi ? w3 : x1);
  P1 = mkfrag(hi ? x6 : w4, hi ? x7 : w5, hi ? w6 : x4, hi ? w7 : x5);
}

// ---------------- prep: fp32 -> bf16 (x), 8 elems/thread ----------------
__global__ __launch_bounds__(256) void k_cvt_x(const float* __restrict__ in, u16* __restrict__ out) {
  int i = blockIdx.x * 256 + threadIdx.x;
  const float4* p = (const float4*)in;
  float4 a = p[i * 2], b = p[i * 2 + 1];
  uint4 o;
  o.x = (u32)f2bf(a.x) | ((u32)f2bf(a.y) << 16);
  o.y = (u32)f2bf(a.z) | ((u32)f2bf(a.w) << 16);
  o.z = (u32)f2bf(b.x) | ((u32)f2bf(b.y) << 16);
  o.w = (u32)f2bf(b.z) | ((u32)f2bf(b.w) << 16);
  ((uint4*)out)[i] = o;
}

// ---------------- prep: transpose + convert: src[R][Cc] f32 -> dst[Cc][R] bf16 ----------------
__global__ __launch_bounds__(256) void k_transpose_cvt(const float* __restrict__ src, u16* __restrict__ dst,
                                                       int R, int Cc) {
  __shared__ float tile[32][33];
  int c0 = blockIdx.x * 32, r0 = blockIdx.y * 32;
  int tx = threadIdx.x, ty = threadIdx.y;   // (32,8)
  #pragma unroll
  for (int j = 0; j < 4; ++j)
    tile[ty * 4 + j][tx] = src[(r0 + ty * 4 + j) * Cc + c0 + tx];
  __syncthreads();
  #pragma unroll
  for (int j = 0; j < 4; ++j) {
    int cl = ty * 4 + j;
    dst[(c0 + cl) * R + r0 + tx] = f2bf(tile[tx][cl]);
  }
}

// ======== 256x256 bf16 GEMM (QKV), K=1024, BK=64, 8-phase schedule (T2+T3+T4+T5) ========
// 8 waves (2M x 4N), per-wave 128x64 out; LDS 128 KB: A[2buf][2half][128][64] + B same.
// Wave M-frags 0-3 in half0 (rows wm*64+..), 4-7 in half1; N-frags 0-1 in Bh0, 2-3 in Bh1.
// Quadrant order per K-tile: (0,0),(0,1),(1,1),(1,0). Each phase stages the half-tile whose
// slot was freed the previous phase; vmcnt(4) at phases 4 and 8 only (2 half-tiles in flight).
// XOR-swizzle (row&7)<<4: linear LDS dest + pre-swizzled global src (rule 21); read key is
// lane-constant (lr&7)<<4 -> conflict-free ds_read_b128.
// Epilogue: cols [0,1024)->q (scaled), [1024,2048)->k, [2048,3072)->vt; per-quadrant LDS repack.
__global__ __launch_bounds__(512, 2) void k_gemm256(const u16* __restrict__ A, const u16* __restrict__ Bt,
                                                    const float* __restrict__ bias,
                                                    u16* __restrict__ oq, u16* __restrict__ ok,
                                                    u16* __restrict__ ovt) {
  __shared__ u16 lds[65536];               // 128 KB
  const int tid = threadIdx.x;
  const int l = tid & 63, w = tid >> 6;
  const int wm = w >> 2, wn = w & 3;       // 2M x 4N
  const int lr = l & 15, lh = l >> 4;
  const int cpx = gridDim.x >> 3;          // 192/8 = 24 (bijective XCD swizzle)
  const int wg = (blockIdx.x & 7) * cpx + (blockIdx.x >> 3);
  const int bn = wg % 12, bm = wg / 12;

  f32x4 acc[8][4] = {};

  // staging: 512 threads x 2 chunks per half-tile (128 rows x 64 K); LDS dest linear,
  // global granule pre-XOR'd with (row&7)
  const int sg0 = (tid & 7) ^ ((tid >> 3) & 7);
  const u16* aB = A  + (bm * 256 + (tid >> 3)) * 1024 + sg0 * 8;
  const u16* bB = Bt + (bn * 256 + (tid >> 3)) * 1024 + sg0 * 8;

  // fragment-read constants
  const int key = (lr & 7) << 4;
  const int cB0 = (lh * 16) ^ key;         // kk=0 byte col (swizzled)
  const int cB1 = (64 + lh * 16) ^ key;    // kk=1
  const int arow0 = wm * 64 + lr;
  const int brow0 = wn * 32 + lr;

  #define STA(h, kt, buf) do {                                                          \
    gload_lds16(aB + ((h) * 128) * 1024 + (kt) * 64, lds + (buf) * 16384 + (h) * 8192 + tid * 8);        \
    gload_lds16(aB + ((h) * 128 + 64) * 1024 + (kt) * 64, lds + (buf) * 16384 + (h) * 8192 + 4096 + tid * 8); \
  } while (0)
  #define STB(h, kt, buf) do {                                                          \
    gload_lds16(bB + ((h) * 128) * 1024 + (kt) * 64, lds + 32768 + (buf) * 16384 + (h) * 8192 + tid * 8);        \
    gload_lds16(bB + ((h) * 128 + 64) * 1024 + (kt) * 64, lds + 32768 + (buf) * 16384 + (h) * 8192 + 4096 + tid * 8); \
  } while (0)

  #define PHASE(buf, mh, nh, STAGE_STMT, FENCE_STMT)                                    \
  {                                                                                     \
    const u16* Ab = lds + (buf) * 16384 + (mh) * 8192;                                  \
    const u16* Bb = lds + 32768 + (buf) * 16384 + (nh) * 8192;                          \
    bf16x8 a_[4][2], b_[2][2];                                                          \
    _Pragma("unroll") for (int m2 = 0; m2 < 4; ++m2) {                                  \
      int rb = (arow0 + m2 * 16) * 128;                                                 \
      a_[m2][0] = *(const bf16x8*)((const char*)Ab + rb + cB0);                         \
      a_[m2][1] = *(const bf16x8*)((const char*)Ab + rb + cB1);                         \
    }                                                                                   \
    _Pragma("unroll") for (int n2 = 0; n2 < 2; ++n2) {                                  \
      int rb = (brow0 + n2 * 16) * 128;                                                 \
      b_[n2][0] = *(const bf16x8*)((const char*)Bb + rb + cB0);                         \
      b_[n2][1] = *(const bf16x8*)((const char*)Bb + rb + cB1);                         \
    }                                                                                   \
    STAGE_STMT;                                                                         \
    __builtin_amdgcn_s_barrier();                                                       \
    asm volatile("s_waitcnt lgkmcnt(0)" ::: "memory");                                  \
    __builtin_amdgcn_sched_barrier(0);                                                  \
    __builtin_amdgcn_s_setprio(1);                                                      \
    _Pragma("unroll") for (int m2 = 0; m2 < 4; ++m2)                                    \
      _Pragma("unroll") for (int n2 = 0; n2 < 2; ++n2) {                                \
        acc[(mh) * 4 + m2][(nh) * 2 + n2] = __builtin_amdgcn_mfma_f32_16x16x32_bf16(    \
            a_[m2][0], b_[n2][0], acc[(mh) * 4 + m2][(nh) * 2 + n2], 0, 0, 0);          \
        acc[(mh) * 4 + m2][(nh) * 2 + n2] = __builtin_amdgcn_mfma_f32_16x16x32_bf16(    \
            a_[m2][1], b_[n2][1], acc[(mh) * 4 + m2][(nh) * 2 + n2], 0, 0, 0);          \
      }                                                                                 \
    __builtin_amdgcn_s_setprio(0);                                                      \
    FENCE_STMT;                                                                         \
    __builtin_amdgcn_s_barrier();                                                       \
    __builtin_amdgcn_sched_barrier(0);                                                  \
  }

  // prologue: tile0 -> buf0 (4 halves), tile1 -> buf1 (Ah0, Bh1); Ah1/Bh0 of tile1 staged in p1/p2
  STA(0, 0, 0); STB(1, 0, 0); STA(1, 0, 0); STB(0, 0, 0);
  STA(0, 1, 1); STB(1, 1, 1);
  asm volatile("s_waitcnt vmcnt(4)" ::: "memory");   // tile0's 8 loads done
  __builtin_amdgcn_s_barrier();
  __builtin_amdgcn_sched_barrier(0);

  for (int it = 0; it < 8; ++it) {
    const int kt1 = 2 * it + 1, ktA = 2 * it + 2, ktB = 2 * it + 3;
    const bool more = (it < 7);
    PHASE(0, 0, 0, { STA(1, kt1, 1); }, {});                               // p1
    PHASE(0, 0, 1, { STB(0, kt1, 1); }, {});                               // p2
    PHASE(0, 1, 1, { if (more) STA(0, ktA, 0); }, {});                     // p3
    PHASE(0, 1, 0, { if (more) STB(1, ktA, 0); },
          { if (more) asm volatile("s_waitcnt vmcnt(4)" ::: "memory");
            else      asm volatile("s_waitcnt vmcnt(0)" ::: "memory"); }); // p4
    PHASE(1, 0, 0, { if (more) STA(1, ktA, 0); }, {});                     // p5
    PHASE(1, 0, 1, { if (more) STB(0, ktA, 0); }, {});                     // p6
    PHASE(1, 1, 1, { if (more) STA(0, ktB, 1); }, {});                     // p7
    PHASE(1, 1, 0, { if (more) STB(1, ktB, 1); },
          { if (more) asm volatile("s_waitcnt vmcnt(4)" ::: "memory");
            else      asm volatile("s_waitcnt vmcnt(0)" ::: "memory"); }); // p8
  }
  #undef PHASE
  #undef STA
  #undef STB

  // -------- epilogue: 4 quadrant rounds through [128][136] LDS repack --------
  const int s = bn >> 2;                   // 0=q, 1=k, 2=v (256-tiles align with 1024 thirds)
  const int row = tid >> 2, q4 = tid & 3;
  if (s < 2) {
    u16* dst = s ? ok : oq;
    const float sc = s ? 1.0f : QSCALE;
    #pragma unroll
    for (int qr = 0; qr < 4; ++qr) {
      const int rh = qr >> 1, chh = qr & 1;
      __syncthreads();
      #pragma unroll
      for (int m2 = 0; m2 < 4; ++m2)
        #pragma unroll
        for (int n2 = 0; n2 < 2; ++n2) {
          f32x4 av = acc[rh * 4 + m2][chh * 2 + n2];
          int cl = wn * 32 + n2 * 16 + lr;
          float bb = bias[bn * 256 + chh * 128 + cl];
          int rl = wm * 64 + m2 * 16 + lh * 4;
          #pragma unroll
          for (int r = 0; r < 4; ++r)
            lds[(rl + r) * 136 + cl] = f2bf((av[r] + bb) * sc);
        }
      __syncthreads();
      int m = bm * 256 + rh * 128 + row;
      int b = m >> 10, n = m & 1023;
      int h0 = ((bn * 256 + chh * 128) & 1023) >> 6;
      const u16* srow2 = lds + row * 136 + q4 * 32;
      u16* drow = dst + ((u32)((b * 16 + h0 + (q4 >> 1)) * 1024) + n) * 64 + (q4 & 1) * 32;
      #pragma unroll
      for (int j = 0; j < 4; ++j)
        *(uint4*)(drow + j * 8) = *(const uint4*)(srow2 + j * 8);
    }
  } else {
    #pragma unroll
    for (int qr = 0; qr < 4; ++qr) {
      const int rh = qr >> 1, chh = qr & 1;
      __syncthreads();
      #pragma unroll
      for (int m2 = 0; m2 < 4; ++m2)
        #pragma unroll
        for (int n2 = 0; n2 < 2; ++n2) {
          f32x4 av = acc[rh * 4 + m2][chh * 2 + n2];
          int cl = wn * 32 + n2 * 16 + lr;
          float bb = bias[bn * 256 + chh * 128 + cl];
          int rl = wm * 64 + m2 * 16 + lh * 4;
          u32 p0 = (u32)f2bf(av[0] + bb) | ((u32)f2bf(av[1] + bb) << 16);
          u32 p1 = (u32)f2bf(av[2] + bb) | ((u32)f2bf(av[3] + bb) << 16);
          uint2 pk; pk.x = p0; pk.y = p1;
          *(uint2*)(lds + cl * 136 + rl) = pk;     // lds[col][row-local] (transpose)
        }
      __syncthreads();
      int c = bn * 256 + chh * 128 + row;          // row = col-local here
      int cc = c & 1023, h = cc >> 6, d = cc & 63;
      int b = (bm * 256) >> 10, n0 = (bm * 256 + rh * 128) & 1023;
      const u16* srow2 = lds + row * 136 + q4 * 32;
      u16* drow = ovt + ((b * 16 + h) * 64 + d) * 1024 + n0 + q4 * 32;
      #pragma unroll
      for (int j = 0; j < 4; ++j)
        *(uint4*)(drow + j * 8) = *(const uint4*)(srow2 + j * 8);
    }
  }
}

// -------- 128x128 bf16 GEMM (proj), K=1024, BK=32, 8 waves, depth-2 prefetch, swizzled LDS -----
template <int EPI, int NBN>
__global__ __launch_bounds__(512) void k_gemm(const u16* __restrict__ A, const u16* __restrict__ Bt,
                                              const float* __restrict__ bias,
                                              u16* __restrict__ oq, u16* __restrict__ ok,
                                              u16* __restrict__ ovt, float* __restrict__ of) {
  __shared__ u16 lds[24576];
  const int tid = threadIdx.x;
  const int l = tid & 63, w = tid >> 6;
  const int wm = w >> 2, wn = w & 3;
  const int lr = l & 15, lh = l >> 4;
  const int cpx = gridDim.x >> 3;
  const int wg = (blockIdx.x & 7) * cpx + (blockIdx.x >> 3);
  const int bn = wg % NBN, bm = wg / NBN;

  f32x4 acc[4][2] = {};
  const int e = tid * 8;
  const int srow = e >> 5;
  const int sgr  = (e >> 3) & 3;
  const int scol = (sgr ^ ((srow >> 1) & 3)) * 8;
  const u16* gA = A + (bm * 128 + srow) * 1024 + scol;
  const u16* gB = Bt + (bn * 128 + srow) * 1024 + scol;

  #define GSTAGE(kk, b)                                              \
    do {                                                             \
      gload_lds16(gA + (kk), lds + (b) * 8192 + e);                  \
      gload_lds16(gB + (kk), lds + (b) * 8192 + 4096 + e);           \
    } while (0)

  GSTAGE(0, 0);
  GSTAGE(32, 1);
  int cur = 0, nxt = 2;

  for (int it = 0; it < 32; ++it) {
    if (it < 31) asm volatile("s_waitcnt vmcnt(2)" ::: "memory");
    else         asm volatile("s_waitcnt vmcnt(0)" ::: "memory");
    __builtin_amdgcn_s_barrier();
    __builtin_amdgcn_sched_barrier(0);

    if (it < 30) GSTAGE((it + 2) * 32, nxt);

    const u16* Asc = lds + cur * 8192;
    bf16x8 af[4], bfr[2];
    #pragma unroll
    for (int mi = 0; mi < 4; ++mi) {
      int r = wm * 64 + mi * 16 + lr;
      af[mi] = *(const bf16x8*)(Asc + r * 32 + ((lh ^ ((r >> 1) & 3)) * 8));
    }
    #pragma unroll
    for (int ni = 0; ni < 2; ++ni) {
      int r = wn * 32 + ni * 16 + lr;
      bfr[ni] = *(const bf16x8*)(Asc + 4096 + r * 32 + ((lh ^ ((r >> 1) & 3)) * 8));
    }
    #pragma unroll
    for (int mi = 0; mi < 4; ++mi)
      #pragma unroll
      for (int ni = 0; ni < 2; ++ni)
        acc[mi][ni] = __builtin_amdgcn_mfma_f32_16x16x32_bf16(af[mi], bfr[ni], acc[mi][ni], 0, 0, 0);

    cur = (cur == 2) ? 0 : cur + 1;
    nxt = (nxt == 2) ? 0 : nxt + 1;
  }
  #undef GSTAGE

  if (EPI == 0) {
    #pragma unroll
    for (int ni = 0; ni < 2; ++ni) {
      int col = bn * 128 + wn * 32 + ni * 16 + lr;
      float bb = bias[col];
      #pragma unroll
      for (int mi = 0; mi < 4; ++mi) {
        int row = bm * 128 + wm * 64 + mi * 16 + lh * 4;
        #pragma unroll
        for (int r = 0; r < 4; ++r)
          of[(row + r) * (NBN * 128) + col] = acc[mi][ni][r] + bb;
      }
    }
  }
}

// -------- flash attention, in-block KV-split x2, max-free softmax (exact merge: common scale) -----
__global__ __launch_bounds__(512) void k_attn(const u16* __restrict__ q, const u16* __restrict__ k,
                                              const u16* __restrict__ vt, u16* __restrict__ ao) {
  __shared__ u16 lds[40960];   // K: [g][2][4096] at 0; V: [g][3][4096] at 16384 (u16 units); 80 KB
  const int tid = threadIdx.x, l = tid & 63, w = tid >> 6;
  const int lq = l & 31, hi = l >> 5;
  const int g = w >> 2, wl = w & 3;
  const int i = blockIdx.x;
  const int bh = (i & 7) * 8 + ((i >> 3) & 7);   // XCD-grouped bh
  const int qb = i >> 6;
  const int t0 = g * 8;

  const int qrow = qb * 128 + wl * 32 + lq;
  const u16* qg = q + bh * 65536 + qrow * 64;
  bf16x8 qf[4];
  #pragma unroll
  for (int ks = 0; ks < 4; ++ks)
    qf[ks] = *(const bf16x8*)(qg + ks * 16 + hi * 8);

  float lsum = 0.f;
  f32x16 o0 = {}, o1 = {};
  bf16x8 pa[4];

  const u16* kg = k + bh * 65536;
  const u16* vg = vt + bh * 65536;

  u16* Kl = lds + g * 8192;
  u16* Vl = lds + 16384 + g * 12288;

  const int tg = tid & 255;
  const int ch0 = tg, ch1 = 256 + tg;
  const int r0_ = ch0 >> 3, s0_ = (ch0 & 7) ^ (r0_ & 7);
  const int r1_ = ch1 >> 3, s1_ = (ch1 & 7) ^ (r1_ & 7);

  #define STAGE(t, kb, vb)                                                         \
    do {                                                                           \
      gload_lds16(kg + (t) * 4096 + r0_ * 64 + s0_ * 8, Kl + (kb) * 4096 + ch0 * 8); \
      gload_lds16(kg + (t) * 4096 + r1_ * 64 + s1_ * 8, Kl + (kb) * 4096 + ch1 * 8); \
      gload_lds16(vg + r0_ * 1024 + (t) * 64 + s0_ * 8, Vl + (vb) * 4096 + ch0 * 8); \
      gload_lds16(vg + r1_ * 1024 + (t) * 64 + s1_ * 8, Vl + (vb) * 4096 + ch1 * 8); \
    } while (0)

  const int swz = (lq & 7) << 4;

  #define QKM(kb, SA, SB)                                                      \
    do {                                                                       \
      const char* Kb = (const char*)(Kl + (kb) * 4096);                        \
      _Pragma("unroll")                                                        \
      for (int ks2 = 0; ks2 < 4; ++ks2) {                                      \
        bf16x8 kf0 = *(const bf16x8*)(Kb + (((lq) * 128 + ks2 * 32 + hi * 16) ^ swz));      \
        bf16x8 kf1 = *(const bf16x8*)(Kb + (((32 + lq) * 128 + ks2 * 32 + hi * 16) ^ swz)); \
        SA = __builtin_amdgcn_mfma_f32_32x32x16_bf16(kf0, qf[ks2], SA, 0, 0, 0); \
        SB = __builtin_amdgcn_mfma_f32_32x32x16_bf16(kf1, qf[ks2], SB, 0, 0, 0); \
      }                                                                        \
    } while (0)

  #define SM(SA, SB)                                                           \
    do {                                                                       \
      float l0 = 0.f, l1 = 0.f, l2 = 0.f, l3 = 0.f;                            \
      _Pragma("unroll") for (int r = 0; r < 16; r += 4) {                      \
        float e0 = __builtin_amdgcn_exp2f(SA[r]);                              \
        float e1 = __builtin_amdgcn_exp2f(SA[r + 1]);                          \
        float e2 = __builtin_amdgcn_exp2f(SA[r + 2]);                          \
        float e3 = __builtin_amdgcn_exp2f(SA[r + 3]);                          \
        SA[r] = e0; SA[r + 1] = e1; SA[r + 2] = e2; SA[r + 3] = e3;            \
        l0 += e0; l1 += e1; l2 += e2; l3 += e3;                                \
      }                                                                        \
      _Pragma("unroll") for (int r = 0; r < 16; r += 4) {                      \
        float e0 = __builtin_amdgcn_exp2f(SB[r]);                              \
        float e1 = __builtin_amdgcn_exp2f(SB[r + 1]);                          \
        float e2 = __builtin_amdgcn_exp2f(SB[r + 2]);                          \
        float e3 = __builtin_amdgcn_exp2f(SB[r + 3]);                          \
        SB[r] = e0; SB[r + 1] = e1; SB[r + 2] = e2; SB[r + 3] = e3;            \
        l0 += e0; l1 += e1; l2 += e2; l3 += e3;                                \
      }                                                                        \
      lsum += (l0 + l1) + (l2 + l3);                                           \
      packP(SA, hi, pa[0], pa[1]);                                             \
      packP(SB, hi, pa[2], pa[3]);                                             \
    } while (0)

  #define PVM(vb)                                                              \
    do {                                                                       \
      const char* Vb = (const char*)(Vl + (vb) * 4096);                        \
      _Pragma("unroll")                                                        \
      for (int ks2 = 0; ks2 < 4; ++ks2) {                                      \
        bf16x8 vf0 = *(const bf16x8*)(Vb + (((lq) * 128 + ks2 * 32 + hi * 16) ^ swz));      \
        bf16x8 vf1 = *(const bf16x8*)(Vb + (((32 + lq) * 128 + ks2 * 32 + hi * 16) ^ swz)); \
        o0 = __builtin_amdgcn_mfma_f32_32x32x16_bf16(pa[ks2], vf0, o0, 0, 0, 0); \
        o1 = __builtin_amdgcn_mfma_f32_32x32x16_bf16(pa[ks2], vf1, o1, 0, 0, 0); \
      }                                                                        \
    } while (0)

  STAGE(t0, 0, 0);
  STAGE(t0 + 1, 1, 1);

  asm volatile("s_waitcnt vmcnt(6)" ::: "memory");
  __builtin_amdgcn_s_barrier();
  __builtin_amdgcn_sched_barrier(0);
  {
    f32x16 sA = {}, sB = {};
    QKM(0, sA, sB);
    SM(sA, sB);
  }

  for (int tl = 0; tl < 7; ++tl) {
    const int vb = tl % 3;
    const int kb1 = (tl + 1) & 1;
    if (tl < 6) asm volatile("s_waitcnt vmcnt(2)" ::: "memory");
    else        asm volatile("s_waitcnt vmcnt(0)" ::: "memory");
    __builtin_amdgcn_s_barrier();
    __builtin_amdgcn_sched_barrier(0);
    if (tl < 6) STAGE(t0 + tl + 2, (tl + 2) & 1, (tl + 2) % 3);

    f32x16 sA = {}, sB = {};
    __builtin_amdgcn_s_setprio(1);
    PVM(vb);
    QKM(kb1, sA, sB);
    __builtin_amdgcn_s_setprio(0);
    SM(sA, sB);
  }
  PVM(1);
  #undef STAGE
  #undef QKM
  #undef SM
  #undef PVM

  lsum += __shfl_xor(lsum, 32);

  __syncthreads();
  float* mf = (float*)lds;
  const int mbase = (wl * 64 + l) * 33;
  if (g == 1) {
    #pragma unroll
    for (int r = 0; r < 16; ++r) { mf[mbase + r] = o0[r]; mf[mbase + 16 + r] = o1[r]; }
    mf[8448 + wl * 64 + l] = lsum;
  }
  __syncthreads();
  if (g == 0) {
    #pragma unroll
    for (int r = 0; r < 16; ++r) { o0[r] += mf[mbase + r]; o1[r] += mf[mbase + 16 + r]; }
    lsum += mf[8448 + wl * 64 + l];

    const int b = bh >> 4, h = bh & 15;
    u16* aob = ao + (u32)(b * 1024 + qb * 128 + wl * 32) * 1024 + h * 64;
    #pragma unroll
    for (int r = 0; r < 16; ++r) {
      int row = (r & 3) + 8 * (r >> 2) + 4 * hi;
      float inv = 1.0f / __shfl(lsum, row, 64);
      aob[row * 1024 + lq]      = f2bf(o0[r] * inv);
      aob[row * 1024 + 32 + lq] = f2bf(o1[r] * inv);
    }
  }
}

// ---------------- launch ----------------
extern "C" void kernel_launch(void* const* d_in, const int* in_sizes, int n_in,
                              void* d_out, int out_size, void* d_ws, size_t ws_size,
                              hipStream_t stream) {
  const float* x      = (const float*)d_in[0];
  const float* w_qkv  = (const float*)d_in[1];
  const float* b_qkv  = (const float*)d_in[2];
  const float* w_proj = (const float*)d_in[3];
  const float* b_proj = (const float*)d_in[4];
  float* out = (float*)d_out;
  char* ws = (char*)d_ws;

  u16* X16   = (u16*)ws;                   //  [4096][1024] bf16 (reused as AO later)
  u16* Wqkv  = (u16*)(ws + 8388608);       //  [3072][1024] bf16
  u16* Wproj = (u16*)(ws + 14680064);      //  [1024][1024] bf16
  u16* Q     = (u16*)(ws + 16777216);      //  [64][1024][64]
  u16* K     = (u16*)(ws + 25165824);      //  [64][1024][64]
  u16* VT    = (u16*)(ws + 33554432);      //  [64][64][1024]
  u16* AO    = X16;

  k_cvt_x<<<dim3(2048), dim3(256), 0, stream>>>(x, X16);
  k_transpose_cvt<<<dim3(96, 32), dim3(32, 8), 0, stream>>>(w_qkv, Wqkv, 1024, 3072);
  k_transpose_cvt<<<dim3(32, 32), dim3(32, 8), 0, stream>>>(w_proj, Wproj, 1024, 1024);
  k_gemm256<<<dim3(192), dim3(512), 0, stream>>>(X16, Wqkv, b_qkv, Q, K, VT);
  k_attn<<<dim3(512), dim3(512), 0, stream>>>(Q, K, VT, AO);
  k_gemm<0, 8><<<dim3(256), dim3(512), 0, stream>>>(AO, Wproj, b_proj, (u16*)0, (u16*)0, (u16*)0, out);
}

// Round 14
// 99.401 us; speedup vs baseline: 1.0521x; 1.0521x over previous
//
#include <hip/hip_runtime.h>

typedef unsigned short u16;
typedef unsigned int u32;
typedef __attribute__((ext_vector_type(8))) short bf16x8;
typedef __attribute__((ext_vector_type(4))) float f32x4;
typedef __attribute__((ext_vector_type(16))) float f32x16;

#define LOG2E 1.4426950408889634f
#define QSCALE (0.125f * LOG2E)

__device__ __forceinline__ u16 f2bf(float f) {
  union { float f; u32 u; } x; x.f = f;
  u32 r = x.u + 0x7fffu + ((x.u >> 16) & 1u);   // RNE; inputs are finite
  return (u16)(r >> 16);
}

__device__ __forceinline__ u32 cvtpk(float a, float b) {
  u32 r;
  asm("v_cvt_pk_bf16_f32 %0, %1, %2" : "=v"(r) : "v"(a), "v"(b));
  return r;
}

__device__ __forceinline__ bf16x8 mkfrag(u32 a, u32 b, u32 c, u32 d) {
  union { u32 w[4]; bf16x8 v; } u;
  u.w[0] = a; u.w[1] = b; u.w[2] = c; u.w[3] = d;
  return u.v;
}

__device__ __forceinline__ void gload_lds16(const void* g, void* l) {
  __builtin_amdgcn_global_load_lds((const __attribute__((address_space(1))) u32*)g,
                                   (__attribute__((address_space(3))) u32*)l, 16, 0, 0);
}

// pack 32 P-values (f32) -> two A-fragments via cvt_pk + lo/hi half exchange (T12)
__device__ __forceinline__ void packP(const f32x16& s, int hi, bf16x8& P0, bf16x8& P1) {
  u32 w0 = cvtpk(s[0], s[1]),  w1 = cvtpk(s[2], s[3]);
  u32 w2 = cvtpk(s[4], s[5]),  w3 = cvtpk(s[6], s[7]);
  u32 w4 = cvtpk(s[8], s[9]),  w5 = cvtpk(s[10], s[11]);
  u32 w6 = cvtpk(s[12], s[13]), w7 = cvtpk(s[14], s[15]);
  u32 x0 = __shfl_xor((int)w0, 32), x1 = __shfl_xor((int)w1, 32);
  u32 x2 = __shfl_xor((int)w2, 32), x3 = __shfl_xor((int)w3, 32);
  u32 x4 = __shfl_xor((int)w4, 32), x5 = __shfl_xor((int)w5, 32);
  u32 x6 = __shfl_xor((int)w6, 32), x7 = __shfl_xor((int)w7, 32);
  P0 = mkfrag(hi ? x2 : w0, hi ? x3 : w1, hi ? w2 : x0, hi ? w3 : x1);
  P1 = mkfrag(hi ? x6 : w4, hi ? x7 : w5, hi ? w6 : x4, hi ? w7 : x5);
}

// ---------------- prep: fp32 -> bf16 (x), 8 elems/thread ----------------
__global__ __launch_bounds__(256) void k_cvt_x(const float* __restrict__ in, u16* __restrict__ out) {
  int i = blockIdx.x * 256 + threadIdx.x;
  const float4* p = (const float4*)in;
  float4 a = p[i * 2], b = p[i * 2 + 1];
  uint4 o;
  o.x = (u32)f2bf(a.x) | ((u32)f2bf(a.y) << 16);
  o.y = (u32)f2bf(a.z) | ((u32)f2bf(a.w) << 16);
  o.z = (u32)f2bf(b.x) | ((u32)f2bf(b.y) << 16);
  o.w = (u32)f2bf(b.z) | ((u32)f2bf(b.w) << 16);
  ((uint4*)out)[i] = o;
}

// ---------------- prep: transpose + convert: src[R][Cc] f32 -> dst[Cc][R] bf16 ----------------
__global__ __launch_bounds__(256) void k_transpose_cvt(const float* __restrict__ src, u16* __restrict__ dst,
                                                       int R, int Cc) {
  __shared__ float tile[32][33];
  int c0 = blockIdx.x * 32, r0 = blockIdx.y * 32;
  int tx = threadIdx.x, ty = threadIdx.y;   // (32,8)
  #pragma unroll
  for (int j = 0; j < 4; ++j)
    tile[ty * 4 + j][tx] = src[(r0 + ty * 4 + j) * Cc + c0 + tx];
  __syncthreads();
  #pragma unroll
  for (int j = 0; j < 4; ++j) {
    int cl = ty * 4 + j;
    dst[(c0 + cl) * R + r0 + tx] = f2bf(tile[tx][cl]);
  }
}

// ======== QKV GEMM: 128x256 tile, K=1024, BK=32, 8 waves of 64x64 (4x4 frags: 0.5 KB LDS/MFMA),
// depth-2 prefetch (3 bufs x 24 KB = 72 KB -> 2 blocks/CU), proven R11 sync skeleton. ========
// A: [4096][1024]; Bt: [3072][1024]. Epilogue thirds: s=bn>>2 (0=q scaled, 1=k, 2=v transposed).
__global__ __launch_bounds__(512, 4) void k_gemmqkv(const u16* __restrict__ A, const u16* __restrict__ Bt,
                                                    const float* __restrict__ bias,
                                                    u16* __restrict__ oq, u16* __restrict__ ok,
                                                    u16* __restrict__ ovt) {
  __shared__ u16 lds[36864];                 // 72 KB staging; epilogue repack reuses (<= 34816 u16)
  const int tid = threadIdx.x;
  const int l = tid & 63, w = tid >> 6;      // 8 waves
  const int wm = w >> 2, wn = w & 3;         // 2M x 4N, per-wave 64x64
  const int lr = l & 15, lh = l >> 4;
  const int cpx = gridDim.x >> 3;            // 384/8 = 48 (bijective XCD swizzle)
  const int wg = (blockIdx.x & 7) * cpx + (blockIdx.x >> 3);
  const int bn = wg % 12, bm = wg / 12;      // 12 N-blocks x 32 M-blocks

  f32x4 acc[4][4] = {};
  // staging: A 128x32 (1 chunk/thread), B 256x32 (2 chunks/thread); LDS dest linear,
  // global granule pre-swizzled with (row>>1)&3 (same family as R6-R11)
  const int rA = tid >> 2, g4 = tid & 3;
  const int sA = (g4 ^ ((rA >> 1) & 3)) * 8;
  const int rB1 = 128 + rA;
  const int sB0 = sA;                                   // same row index => same swizzle
  const int sB1 = (g4 ^ ((rB1 >> 1) & 3)) * 8;
  const u16* gAp  = A  + (bm * 128 + rA) * 1024 + sA;
  const u16* gBp0 = Bt + (bn * 256 + rA) * 1024 + sB0;
  const u16* gBp1 = Bt + (bn * 256 + rB1) * 1024 + sB1;

  #define GSTAGE(kk, b)                                                \
    do {                                                               \
      gload_lds16(gAp  + (kk), lds + (b) * 12288 + tid * 8);           \
      gload_lds16(gBp0 + (kk), lds + (b) * 12288 + 4096 + tid * 8);    \
      gload_lds16(gBp1 + (kk), lds + (b) * 12288 + 8192 + tid * 8);    \
    } while (0)

  GSTAGE(0, 0);
  GSTAGE(32, 1);
  int cur = 0, nxt = 2;

  for (int it = 0; it < 32; ++it) {
    if (it < 31) asm volatile("s_waitcnt vmcnt(3)" ::: "memory");   // this tile's 3 loads (oldest) done
    else         asm volatile("s_waitcnt vmcnt(0)" ::: "memory");
    __builtin_amdgcn_s_barrier();
    __builtin_amdgcn_sched_barrier(0);

    if (it < 30) GSTAGE((it + 2) * 32, nxt);

    const u16* Asc = lds + cur * 12288;
    bf16x8 af[4], bfr[4];
    #pragma unroll
    for (int mi = 0; mi < 4; ++mi) {
      int r = wm * 64 + mi * 16 + lr;
      af[mi] = *(const bf16x8*)(Asc + r * 32 + ((lh ^ ((r >> 1) & 3)) * 8));
    }
    #pragma unroll
    for (int ni = 0; ni < 4; ++ni) {
      int r = wn * 64 + ni * 16 + lr;
      bfr[ni] = *(const bf16x8*)(Asc + 4096 + r * 32 + ((lh ^ ((r >> 1) & 3)) * 8));
    }
    #pragma unroll
    for (int mi = 0; mi < 4; ++mi)
      #pragma unroll
      for (int ni = 0; ni < 4; ++ni)
        acc[mi][ni] = __builtin_amdgcn_mfma_f32_16x16x32_bf16(af[mi], bfr[ni], acc[mi][ni], 0, 0, 0);

    cur = (cur == 2) ? 0 : cur + 1;
    nxt = (nxt == 2) ? 0 : nxt + 1;
  }
  #undef GSTAGE

  const int s = bn >> 2;                 // third: 0=q, 1=k, 2=v (256-tile stays inside one third)
  __syncthreads();                       // staging LDS dead; reuse for repack
  if (s < 2) {
    // repack [128][264] (stride-264 u16), then coalesced uint4 row stores (4 heads per tile)
    u16* dst = (s == 0) ? oq : ok;
    const float sc = (s == 0) ? QSCALE : 1.0f;
    #pragma unroll
    for (int ni = 0; ni < 4; ++ni) {
      int cl = wn * 64 + ni * 16 + lr;
      float bb = bias[bn * 256 + cl];
      #pragma unroll
      for (int mi = 0; mi < 4; ++mi) {
        int rl = wm * 64 + mi * 16 + lh * 4;
        #pragma unroll
        for (int r = 0; r < 4; ++r)
          lds[(rl + r) * 264 + cl] = f2bf((acc[mi][ni][r] + bb) * sc);
      }
    }
    __syncthreads();
    const int row = tid >> 2, q4 = tid & 3;            // q4 = head chunk (64 cols)
    const int h0 = ((bn * 256) & 1023) >> 6;
    const int m = bm * 128 + row, b = m >> 10, n = m & 1023;
    const u16* srow2 = lds + row * 264 + q4 * 64;
    u16* drow = dst + ((u32)((b * 16 + h0 + q4) * 1024) + n) * 64;
    #pragma unroll
    for (int j = 0; j < 8; ++j)
      *(uint4*)(drow + j * 8) = *(const uint4*)(srow2 + j * 8);
  } else {
    // v: transpose 128x256 tile via LDS [256][136], write [bh][d][n] coalesced
    #pragma unroll
    for (int ni = 0; ni < 4; ++ni) {
      int cl = wn * 64 + ni * 16 + lr;
      float bb = bias[bn * 256 + cl];
      #pragma unroll
      for (int mi = 0; mi < 4; ++mi) {
        int rl = wm * 64 + mi * 16 + lh * 4;
        u32 p0 = (u32)f2bf(acc[mi][ni][0] + bb) | ((u32)f2bf(acc[mi][ni][1] + bb) << 16);
        u32 p1 = (u32)f2bf(acc[mi][ni][2] + bb) | ((u32)f2bf(acc[mi][ni][3] + bb) << 16);
        uint2 pk; pk.x = p0; pk.y = p1;
        *(uint2*)(lds + cl * 136 + rl) = pk;
      }
    }
    __syncthreads();
    const int cl = tid >> 1, half = tid & 1;           // 256 cols x 2 halves of 64 n-elems
    const int c = bn * 256 + cl, cc = c & 1023, h = cc >> 6, d = cc & 63;
    const int b = (bm * 128) >> 10, n0 = (bm * 128) & 1023;
    const u16* srow2 = lds + cl * 136 + half * 64;
    u16* drow = ovt + ((b * 16 + h) * 64 + d) * 1024 + n0 + half * 64;
    #pragma unroll
    for (int j = 0; j < 8; ++j)                        // FIX R13: was j<4 (half of VT unwritten)
      *(uint4*)(drow + j * 8) = *(const uint4*)(srow2 + j * 8);
  }
}

// -------- 128x128 bf16 GEMM (proj), K=1024, BK=32, 8 waves, depth-2 prefetch, swizzled LDS -----
template <int NBN>
__global__ __launch_bounds__(512) void k_gemm(const u16* __restrict__ A, const u16* __restrict__ Bt,
                                              const float* __restrict__ bias, float* __restrict__ of) {
  __shared__ u16 lds[24576];
  const int tid = threadIdx.x;
  const int l = tid & 63, w = tid >> 6;
  const int wm = w >> 2, wn = w & 3;
  const int lr = l & 15, lh = l >> 4;
  const int cpx = gridDim.x >> 3;
  const int wg = (blockIdx.x & 7) * cpx + (blockIdx.x >> 3);
  const int bn = wg % NBN, bm = wg / NBN;

  f32x4 acc[4][2] = {};
  const int e = tid * 8;
  const int srow = e >> 5;
  const int sgr  = (e >> 3) & 3;
  const int scol = (sgr ^ ((srow >> 1) & 3)) * 8;
  const u16* gA = A + (bm * 128 + srow) * 1024 + scol;
  const u16* gB = Bt + (bn * 128 + srow) * 1024 + scol;

  #define GSTAGE(kk, b)                                              \
    do {                                                             \
      gload_lds16(gA + (kk), lds + (b) * 8192 + e);                  \
      gload_lds16(gB + (kk), lds + (b) * 8192 + 4096 + e);           \
    } while (0)

  GSTAGE(0, 0);
  GSTAGE(32, 1);
  int cur = 0, nxt = 2;

  for (int it = 0; it < 32; ++it) {
    if (it < 31) asm volatile("s_waitcnt vmcnt(2)" ::: "memory");
    else         asm volatile("s_waitcnt vmcnt(0)" ::: "memory");
    __builtin_amdgcn_s_barrier();
    __builtin_amdgcn_sched_barrier(0);

    if (it < 30) GSTAGE((it + 2) * 32, nxt);

    const u16* Asc = lds + cur * 8192;
    bf16x8 af[4], bfr[2];
    #pragma unroll
    for (int mi = 0; mi < 4; ++mi) {
      int r = wm * 64 + mi * 16 + lr;
      af[mi] = *(const bf16x8*)(Asc + r * 32 + ((lh ^ ((r >> 1) & 3)) * 8));
    }
    #pragma unroll
    for (int ni = 0; ni < 2; ++ni) {
      int r = wn * 32 + ni * 16 + lr;
      bfr[ni] = *(const bf16x8*)(Asc + 4096 + r * 32 + ((lh ^ ((r >> 1) & 3)) * 8));
    }
    #pragma unroll
    for (int mi = 0; mi < 4; ++mi)
      #pragma unroll
      for (int ni = 0; ni < 2; ++ni)
        acc[mi][ni] = __builtin_amdgcn_mfma_f32_16x16x32_bf16(af[mi], bfr[ni], acc[mi][ni], 0, 0, 0);

    cur = (cur == 2) ? 0 : cur + 1;
    nxt = (nxt == 2) ? 0 : nxt + 1;
  }
  #undef GSTAGE

  #pragma unroll
  for (int ni = 0; ni < 2; ++ni) {
    int col = bn * 128 + wn * 32 + ni * 16 + lr;
    float bb = bias[col];
    #pragma unroll
    for (int mi = 0; mi < 4; ++mi) {
      int row = bm * 128 + wm * 64 + mi * 16 + lh * 4;
      #pragma unroll
      for (int r = 0; r < 4; ++r)
        of[(row + r) * (NBN * 128) + col] = acc[mi][ni][r] + bb;
    }
  }
}

// -------- flash attention, in-block KV-split x2, max-free softmax (exact merge: common scale) -----
__global__ __launch_bounds__(512) void k_attn(const u16* __restrict__ q, const u16* __restrict__ k,
                                              const u16* __restrict__ vt, u16* __restrict__ ao) {
  __shared__ u16 lds[40960];   // K: [g][2][4096] at 0; V: [g][3][4096] at 16384 (u16 units); 80 KB
  const int tid = threadIdx.x, l = tid & 63, w = tid >> 6;
  const int lq = l & 31, hi = l >> 5;
  const int g = w >> 2, wl = w & 3;
  const int i = blockIdx.x;
  const int bh = (i & 7) * 8 + ((i >> 3) & 7);   // XCD-grouped bh
  const int qb = i >> 6;
  const int t0 = g * 8;

  const int qrow = qb * 128 + wl * 32 + lq;
  const u16* qg = q + bh * 65536 + qrow * 64;
  bf16x8 qf[4];
  #pragma unroll
  for (int ks = 0; ks < 4; ++ks)
    qf[ks] = *(const bf16x8*)(qg + ks * 16 + hi * 8);

  float lsum = 0.f;
  f32x16 o0 = {}, o1 = {};
  bf16x8 pa[4];

  const u16* kg = k + bh * 65536;
  const u16* vg = vt + bh * 65536;

  u16* Kl = lds + g * 8192;
  u16* Vl = lds + 16384 + g * 12288;

  const int tg = tid & 255;
  const int ch0 = tg, ch1 = 256 + tg;
  const int r0_ = ch0 >> 3, s0_ = (ch0 & 7) ^ (r0_ & 7);
  const int r1_ = ch1 >> 3, s1_ = (ch1 & 7) ^ (r1_ & 7);

  #define STAGE(t, kb, vb)                                                         \
    do {                                                                           \
      gload_lds16(kg + (t) * 4096 + r0_ * 64 + s0_ * 8, Kl + (kb) * 4096 + ch0 * 8); \
      gload_lds16(kg + (t) * 4096 + r1_ * 64 + s1_ * 8, Kl + (kb) * 4096 + ch1 * 8); \
      gload_lds16(vg + r0_ * 1024 + (t) * 64 + s0_ * 8, Vl + (vb) * 4096 + ch0 * 8); \
      gload_lds16(vg + r1_ * 1024 + (t) * 64 + s1_ * 8, Vl + (vb) * 4096 + ch1 * 8); \
    } while (0)

  const int swz = (lq & 7) << 4;

  #define QKM(kb, SA, SB)                                                      \
    do {                                                                       \
      const char* Kb = (const char*)(Kl + (kb) * 4096);                        \
      _Pragma("unroll")                                                        \
      for (int ks2 = 0; ks2 < 4; ++ks2) {                                      \
        bf16x8 kf0 = *(const bf16x8*)(Kb + (((lq) * 128 + ks2 * 32 + hi * 16) ^ swz));      \
        bf16x8 kf1 = *(const bf16x8*)(Kb + (((32 + lq) * 128 + ks2 * 32 + hi * 16) ^ swz)); \
        SA = __builtin_amdgcn_mfma_f32_32x32x16_bf16(kf0, qf[ks2], SA, 0, 0, 0); \
        SB = __builtin_amdgcn_mfma_f32_32x32x16_bf16(kf1, qf[ks2], SB, 0, 0, 0); \
      }                                                                        \
    } while (0)

  #define SM(SA, SB)                                                           \
    do {                                                                       \
      float l0 = 0.f, l1 = 0.f, l2 = 0.f, l3 = 0.f;                            \
      _Pragma("unroll") for (int r = 0; r < 16; r += 4) {                      \
        float e0 = __builtin_amdgcn_exp2f(SA[r]);                              \
        float e1 = __builtin_amdgcn_exp2f(SA[r + 1]);                          \
        float e2 = __builtin_amdgcn_exp2f(SA[r + 2]);                          \
        float e3 = __builtin_amdgcn_exp2f(SA[r + 3]);                          \
        SA[r] = e0; SA[r + 1] = e1; SA[r + 2] = e2; SA[r + 3] = e3;            \
        l0 += e0; l1 += e1; l2 += e2; l3 += e3;                                \
      }                                                                        \
      _Pragma("unroll") for (int r = 0; r < 16; r += 4) {                      \
        float e0 = __builtin_amdgcn_exp2f(SB[r]);                              \
        float e1 = __builtin_amdgcn_exp2f(SB[r + 1]);                          \
        float e2 = __builtin_amdgcn_exp2f(SB[r + 2]);                          \
        float e3 = __builtin_amdgcn_exp2f(SB[r + 3]);                          \
        SB[r] = e0; SB[r + 1] = e1; SB[r + 2] = e2; SB[r + 3] = e3;            \
        l0 += e0; l1 += e1; l2 += e2; l3 += e3;                                \
      }                                                                        \
      lsum += (l0 + l1) + (l2 + l3);                                           \
      packP(SA, hi, pa[0], pa[1]);                                             \
      packP(SB, hi, pa[2], pa[3]);                                             \
    } while (0)

  #define PVM(vb)                                                              \
    do {                                                                       \
      const char* Vb = (const char*)(Vl + (vb) * 4096);                        \
      _Pragma("unroll")                                                        \
      for (int ks2 = 0; ks2 < 4; ++ks2) {                                      \
        bf16x8 vf0 = *(const bf16x8*)(Vb + (((lq) * 128 + ks2 * 32 + hi * 16) ^ swz));      \
        bf16x8 vf1 = *(const bf16x8*)(Vb + (((32 + lq) * 128 + ks2 * 32 + hi * 16) ^ swz)); \
        o0 = __builtin_amdgcn_mfma_f32_32x32x16_bf16(pa[ks2], vf0, o0, 0, 0, 0); \
        o1 = __builtin_amdgcn_mfma_f32_32x32x16_bf16(pa[ks2], vf1, o1, 0, 0, 0); \
      }                                                                        \
    } while (0)

  STAGE(t0, 0, 0);
  STAGE(t0 + 1, 1, 1);

  asm volatile("s_waitcnt vmcnt(6)" ::: "memory");
  __builtin_amdgcn_s_barrier();
  __builtin_amdgcn_sched_barrier(0);
  {
    f32x16 sA = {}, sB = {};
    QKM(0, sA, sB);
    SM(sA, sB);
  }

  for (int tl = 0; tl < 7; ++tl) {
    const int vb = tl % 3;
    const int kb1 = (tl + 1) & 1;
    if (tl < 6) asm volatile("s_waitcnt vmcnt(2)" ::: "memory");
    else        asm volatile("s_waitcnt vmcnt(0)" ::: "memory");
    __builtin_amdgcn_s_barrier();
    __builtin_amdgcn_sched_barrier(0);
    if (tl < 6) STAGE(t0 + tl + 2, (tl + 2) & 1, (tl + 2) % 3);

    f32x16 sA = {}, sB = {};
    __builtin_amdgcn_s_setprio(1);
    PVM(vb);
    QKM(kb1, sA, sB);
    __builtin_amdgcn_s_setprio(0);
    SM(sA, sB);
  }
  PVM(1);
  #undef STAGE
  #undef QKM
  #undef SM
  #undef PVM

  lsum += __shfl_xor(lsum, 32);

  __syncthreads();
  float* mf = (float*)lds;
  const int mbase = (wl * 64 + l) * 33;
  if (g == 1) {
    #pragma unroll
    for (int r = 0; r < 16; ++r) { mf[mbase + r] = o0[r]; mf[mbase + 16 + r] = o1[r]; }
    mf[8448 + wl * 64 + l] = lsum;
  }
  __syncthreads();
  if (g == 0) {
    #pragma unroll
    for (int r = 0; r < 16; ++r) { o0[r] += mf[mbase + r]; o1[r] += mf[mbase + 16 + r]; }
    lsum += mf[8448 + wl * 64 + l];

    const int b = bh >> 4, h = bh & 15;
    u16* aob = ao + (u32)(b * 1024 + qb * 128 + wl * 32) * 1024 + h * 64;
    #pragma unroll
    for (int r = 0; r < 16; ++r) {
      int row = (r & 3) + 8 * (r >> 2) + 4 * hi;
      float inv = 1.0f / __shfl(lsum, row, 64);
      aob[row * 1024 + lq]      = f2bf(o0[r] * inv);
      aob[row * 1024 + 32 + lq] = f2bf(o1[r] * inv);
    }
  }
}

// ---------------- launch ----------------
extern "C" void kernel_launch(void* const* d_in, const int* in_sizes, int n_in,
                              void* d_out, int out_size, void* d_ws, size_t ws_size,
                              hipStream_t stream) {
  const float* x      = (const float*)d_in[0];
  const float* w_qkv  = (const float*)d_in[1];
  const float* b_qkv  = (const float*)d_in[2];
  const float* w_proj = (const float*)d_in[3];
  const float* b_proj = (const float*)d_in[4];
  float* out = (float*)d_out;
  char* ws = (char*)d_ws;

  u16* X16   = (u16*)ws;                   //  [4096][1024] bf16 (reused as AO later)
  u16* Wqkv  = (u16*)(ws + 8388608);       //  [3072][1024] bf16
  u16* Wproj = (u16*)(ws + 14680064);      //  [1024][1024] bf16
  u16* Q     = (u16*)(ws + 16777216);      //  [64][1024][64]
  u16* K     = (u16*)(ws + 25165824);      //  [64][1024][64]
  u16* VT    = (u16*)(ws + 33554432);      //  [64][64][1024]
  u16* AO    = X16;

  k_cvt_x<<<dim3(2048), dim3(256), 0, stream>>>(x, X16);
  k_transpose_cvt<<<dim3(96, 32), dim3(32, 8), 0, stream>>>(w_qkv, Wqkv, 1024, 3072);
  k_transpose_cvt<<<dim3(32, 32), dim3(32, 8), 0, stream>>>(w_proj, Wproj, 1024, 1024);
  k_gemmqkv<<<dim3(384), dim3(512), 0, stream>>>(X16, Wqkv, b_qkv, Q, K, VT);
  k_attn<<<dim3(512), dim3(512), 0, stream>>>(Q, K, VT, AO);
  k_gemm<8><<<dim3(256), dim3(512), 0, stream>>>(AO, Wproj, b_proj, out);
}